// Round 7
// baseline (630.929 us; speedup 1.0000x reference)
//
#include <hip/hip_runtime.h>
#include <cstdint>

// Problem constants (B, BS, M, D) = (64, 8, 512, 256), neg = B/BS = 8
#define NEG_FILL_F (-10000000000.0f)
constexpr int BB     = 64;
constexpr int BS_    = 8;
constexpr int MM     = 512;
constexpr int DD     = 256;
constexpr int ROWS_X = BB * MM;           // 32768
constexpr int ROWS_Y = BS_ * MM;          // 4096
constexpr int ROWS_ALL = ROWS_X + ROWS_Y; // 36864

typedef __attribute__((ext_vector_type(8))) short short8;   // 8 bf16 = 4 VGPRs
typedef __attribute__((ext_vector_type(4))) float f32x4;    // MFMA C/D

__device__ inline unsigned short rne_bf16(float f) {
    unsigned int u = __float_as_uint(f);
    u = (u + 0x7FFFu + ((u >> 16) & 1u)) >> 16;
    return (unsigned short)u;
}
__device__ inline float bf2f(unsigned short h) {
    return __uint_as_float(((unsigned int)h) << 16);
}
__device__ inline f32x4 mfma16(short8 a, short8 b, f32x4 c) {
    return __builtin_amdgcn_mfma_f32_16x16x32_bf16(a, b, c, 0, 0, 0);
}
// Async global->LDS 16B DMA. LDS dst wave-uniform base; HW adds lane*16.
__device__ inline void gld16(const unsigned short* g, unsigned short* l) {
    __builtin_amdgcn_global_load_lds(
        (const __attribute__((address_space(1))) unsigned int*)g,
        (__attribute__((address_space(3))) unsigned int*)l, 16, 0, 0);
}

// Fragment loads + 16 MFMAs. LDS T[row][k] row-major, unpadded (gld16 layout).
// A: lane holds A[m=lid][k=quad*8+j]; B: B[k=quad*8+j][n=lid].
template<int LDA, int LDB>
__device__ inline void mfma_tiles(const unsigned short (*Ab)[LDA],
                                  const unsigned short (*Bb)[LDB],
                                  int kk, int wrow, int wcol, int lid, int quad,
                                  f32x4 acc[4][4])
{
    short8 af[4], bfr[4];
    #pragma unroll
    for (int i = 0; i < 4; ++i)
        af[i] = *(const short8*)&Ab[wrow + i * 16 + lid][kk + quad * 8];
    #pragma unroll
    for (int j = 0; j < 4; ++j)
        bfr[j] = *(const short8*)&Bb[wcol + j * 16 + lid][kk + quad * 8];
    #pragma unroll
    for (int i = 0; i < 4; ++i)
        #pragma unroll
        for (int j = 0; j < 4; ++j)
            acc[i][j] = mfma16(af[i], bfr[j], acc[i][j]);
}

// Async-stage a 128-row x 64-short tile from a stride-256 bf16 plane.
// src pre-offset to tile origin. Chunk c -> LDS byte c*16 (lane-contiguous).
__device__ inline void stage64_async(unsigned short* dstbase,
                                     const unsigned short* __restrict__ src,
                                     int wave, int lane)
{
    #pragma unroll
    for (int s = 0; s < 4; ++s) {
        const int c   = s * 256 + wave * 64 + lane;  // 0..1023
        const int row = c >> 3;
        const int off = (c & 7) * 8;
        gld16(src + (size_t)row * 256 + off,
              dstbase + (size_t)(s * 256 + wave * 64) * 8);
    }
}

// ---------------------------------------------------------------------------
// Split fp32 -> bf16 (h, l) planes: x||y -> Xh/Xl [36864][256],
// Wq/Wk/Wv -> Wh/Wl [3][256][256]. grid = 4704 x 256, 8 elems/thread.
// ---------------------------------------------------------------------------
__global__ __launch_bounds__(256) void conv_kernel(
    const float* __restrict__ x, const float* __restrict__ y,
    const float* __restrict__ Wq, const float* __restrict__ Wk,
    const float* __restrict__ Wv,
    unsigned short* __restrict__ Xh, unsigned short* __restrict__ Xl,
    unsigned short* __restrict__ Wh, unsigned short* __restrict__ Wl)
{
    const size_t e = ((size_t)blockIdx.x * 256 + threadIdx.x) * 8;
    const float* src; unsigned short *dh, *dl;
    if (e < 9437184) {                       // x/y region (36864*256)
        src = (e < 8388608) ? (x + e) : (y + (e - 8388608));
        dh = Xh + e; dl = Xl + e;
    } else {                                 // W region (3*65536)
        const size_t ew = e - 9437184;
        const int zi = (int)(ew >> 16);
        src = (zi == 0 ? Wq : zi == 1 ? Wk : Wv) + (ew & 65535);
        dh = Wh + ew; dl = Wl + ew;
    }
    float4 v0 = *(const float4*)src;
    float4 v1 = *(const float4*)(src + 4);
    const float fv[8] = {v0.x, v0.y, v0.z, v0.w, v1.x, v1.y, v1.z, v1.w};
    short8 h8, l8;
    #pragma unroll
    for (int i = 0; i < 8; ++i) {
        unsigned short h = rne_bf16(fv[i]);
        h8[i] = (short)h;
        l8[i] = (short)rne_bf16(fv[i] - bf2f(h));
    }
    *(short8*)dh = h8;
    *(short8*)dl = l8;
}

// ---------------------------------------------------------------------------
// Projections via MFMA, K'=768 as 3 group-sections (Ah*Bh + Ah*Bl + Al*Bh).
// Pure async staging both operands. Epilogues via bank-swizzled LDS transpose
// -> fully coalesced short8 stores. z=0 -> Qh/Ql, z=1 -> Kh/Kl,
// z=2 -> Vt[b][d][token]. grid = (288, 2, 3)
// ---------------------------------------------------------------------------
__global__ __launch_bounds__(256) void proj_kernel(
    const unsigned short* __restrict__ Xh, const unsigned short* __restrict__ Xl,
    const unsigned short* __restrict__ Wh, const unsigned short* __restrict__ Wl,
    unsigned short* __restrict__ Qh, unsigned short* __restrict__ Ql,
    unsigned short* __restrict__ Kh, unsigned short* __restrict__ Kl,
    unsigned short* __restrict__ Vt)
{
    const int z    = blockIdx.z;
    const int row0 = blockIdx.x * 128;
    const int col0 = blockIdx.y * 128;
    const unsigned short* WhP = Wh + (size_t)z * 65536;
    const unsigned short* WlP = Wl + (size_t)z * 65536;

    __shared__ unsigned short POOL[16384];   // K-loop: Ab|Bb; epilogue: 128x128
    unsigned short (*Ab)[64] = (unsigned short (*)[64])POOL;
    unsigned short (*Bb)[64] = (unsigned short (*)[64])(POOL + 8192);

    const int t = threadIdx.x;
    const int wave = t >> 6, lane = t & 63, quad = lane >> 4, lid = lane & 15;
    const int wrow = (wave & 1) * 64, wcol = (wave >> 1) * 64;

    f32x4 acc[4][4];
    #pragma unroll
    for (int i = 0; i < 4; ++i)
        #pragma unroll
        for (int j = 0; j < 4; ++j) acc[i][j] = (f32x4){0.f, 0.f, 0.f, 0.f};

    // sections: s0=(Xh,Wh), s1=(Xh,Wl), s2=(Xl,Wh)
    for (int ck = 0; ck < 12; ++ck) {
        const int s  = ck >> 2;
        const int d0 = (ck & 3) * 64;
        const unsigned short* Ap = (s == 2 ? Xl : Xh) + (size_t)row0 * 256 + d0;
        const unsigned short* Bp = (s == 1 ? WlP : WhP) + (size_t)col0 * 256 + d0;
        stage64_async(&Ab[0][0], Ap, wave, lane);
        stage64_async(&Bb[0][0], Bp, wave, lane);
        __syncthreads();
        mfma_tiles<64,64>(Ab, Bb, 0,  wrow, wcol, lid, quad, acc);
        mfma_tiles<64,64>(Ab, Bb, 32, wrow, wcol, lid, quad, acc);
        __syncthreads();
    }

    if (z == 2) {
        // Vt: LDS [d][token], swizzled token; lane's 4 C-rows = contiguous tokens
        #pragma unroll
        for (int i = 0; i < 4; ++i) {
            const int tok0 = wrow + i * 16 + quad * 4;
            #pragma unroll
            for (int jt = 0; jt < 4; ++jt) {
                const int d  = wcol + jt * 16 + lid;
                const int sw = ((d >> 2) & 7) << 4;
                unsigned int lo = (unsigned)rne_bf16(acc[i][jt][0]) |
                                  ((unsigned)rne_bf16(acc[i][jt][1]) << 16);
                unsigned int hi = (unsigned)rne_bf16(acc[i][jt][2]) |
                                  ((unsigned)rne_bf16(acc[i][jt][3]) << 16);
                *(uint2*)&POOL[d * 128 + (tok0 ^ sw)] = make_uint2(lo, hi);
            }
        }
        __syncthreads();
        const int dloc = t >> 1, cb = (t & 1) * 64;
        const int sw = ((dloc >> 2) & 7) << 4;
        const int b = row0 >> 9, j0 = row0 & 511;
        unsigned short* gdst = Vt + ((size_t)b * DD + col0 + dloc) * MM + j0 + cb;
        #pragma unroll
        for (int g = 0; g < 8; ++g) {
            short8 v = *(const short8*)&POOL[dloc * 128 + ((cb + g * 8) ^ sw)];
            *(short8*)(gdst + g * 8) = v;
        }
    } else {
        unsigned short* dstH = (z == 0) ? Qh : Kh;
        unsigned short* dstL = (z == 0) ? Ql : Kl;
        #pragma unroll
        for (int p = 0; p < 2; ++p) {
            // scatter into swizzled [row][col] LDS (b16 writes, banks spread)
            #pragma unroll
            for (int i = 0; i < 4; ++i) {
                const int rl = wrow + i * 16 + quad * 4;
                #pragma unroll
                for (int r = 0; r < 4; ++r) {
                    const int row = rl + r;
                    const int sw  = ((row >> 2) & 7) << 4;
                    #pragma unroll
                    for (int jt = 0; jt < 4; ++jt) {
                        const int col = wcol + jt * 16 + lid;
                        const float v = acc[i][jt][r];
                        const unsigned short h = rne_bf16(v);
                        POOL[row * 128 + (col ^ sw)] =
                            (p == 0) ? h : rne_bf16(v - bf2f(h));
                    }
                }
            }
            __syncthreads();
            const int rr = t >> 1, cb = (t & 1) * 64;
            const int sw = ((rr >> 2) & 7) << 4;
            unsigned short* gdst = (p == 0 ? dstH : dstL)
                                 + (size_t)(row0 + rr) * 256 + col0 + cb;
            #pragma unroll
            for (int g = 0; g < 8; ++g) {
                short8 v = *(const short8*)&POOL[rr * 128 + ((cb + g * 8) ^ sw)];
                *(short8*)(gdst + g * 8) = v;
            }
            __syncthreads();
        }
    }
}

// ---------------------------------------------------------------------------
// Scores via MFMA (3 sections: QhKh + QhKl + QlKh), pure async staging,
// mask+S epilogue (64B-sector stores) + fused softmax partials.
// mode 0: x-self; 1: y-self; 2: xy (bq=s*8+n, bk=s). grid = (4, 4, nbatch)
// ---------------------------------------------------------------------------
__global__ __launch_bounds__(256) void scores_kernel(
    const unsigned short* __restrict__ Qh_, const unsigned short* __restrict__ Ql_,
    const unsigned short* __restrict__ Kh_, const unsigned short* __restrict__ Kl_,
    const int* __restrict__ mq_base, const int* __restrict__ mk_base,
    float* __restrict__ Sbase, float2* __restrict__ pstats, int mode)
{
    const int z = blockIdx.z;
    int bq, bk;
    if (mode == 2) { const int n = z >> 3, s = z & 7; bq = s * 8 + n; bk = s; }
    else           { bq = z; bk = z; }

    const int row0 = blockIdx.x * 128;
    const int col0 = blockIdx.y * 128;
    const size_t aoff = (size_t)(bq * MM + row0) * 256;
    const size_t boff = (size_t)(bk * MM + col0) * 256;
    const int* mq = mq_base + bq * MM;
    const int* mk = mk_base + bk * MM;
    float* S = Sbase + (size_t)z * MM * MM;

    __shared__ unsigned short POOL[16384];
    unsigned short (*Ab)[64] = (unsigned short (*)[64])POOL;
    unsigned short (*Bb)[64] = (unsigned short (*)[64])(POOL + 8192);
    __shared__ float pm2[128][2];
    __shared__ float ps2[128][2];

    const int t = threadIdx.x;
    const int wave = t >> 6, lane = t & 63, quad = lane >> 4, lid = lane & 15;
    const int wrow = (wave & 1) * 64, wcol = (wave >> 1) * 64;

    f32x4 acc[4][4];
    #pragma unroll
    for (int i = 0; i < 4; ++i)
        #pragma unroll
        for (int j = 0; j < 4; ++j) acc[i][j] = (f32x4){0.f, 0.f, 0.f, 0.f};

    // sections: s0=(Qh,Kh), s1=(Qh,Kl), s2=(Ql,Kh)
    for (int ck = 0; ck < 12; ++ck) {
        const int s  = ck >> 2;
        const int d0 = (ck & 3) * 64;
        const unsigned short* Ap = (s == 2 ? Ql_ : Qh_) + aoff + d0;
        const unsigned short* Bp = (s == 1 ? Kl_ : Kh_) + boff + d0;
        stage64_async(&Ab[0][0], Ap, wave, lane);
        stage64_async(&Bb[0][0], Bp, wave, lane);
        __syncthreads();
        mfma_tiles<64,64>(Ab, Bb, 0,  wrow, wcol, lid, quad, acc);
        mfma_tiles<64,64>(Ab, Bb, 32, wrow, wcol, lid, quad, acc);
        __syncthreads();
    }

    int mcol[4];
    #pragma unroll
    for (int jt = 0; jt < 4; ++jt) mcol[jt] = mk[col0 + wcol + jt * 16 + lid];

    #pragma unroll
    for (int i = 0; i < 4; ++i) {
        const int rl0 = wrow + i * 16 + quad * 4;
        #pragma unroll
        for (int r = 0; r < 4; ++r) {
            const int rlocal = rl0 + r;
            const int rg = row0 + rlocal;
            const bool mr = (mq[rg] != 0);
            float* Srow = S + (size_t)rg * MM;
            float v[4];
            float mt = -3.4e38f;
            #pragma unroll
            for (int jt = 0; jt < 4; ++jt) {
                const int col = col0 + wcol + jt * 16 + lid;
                const bool valid = mr && (mcol[jt] != 0);
                v[jt] = valid ? acc[i][jt][r] : NEG_FILL_F;
                Srow[col] = v[jt];
                mt = fmaxf(mt, v[jt]);
            }
            #pragma unroll
            for (int o = 1; o < 16; o <<= 1) mt = fmaxf(mt, __shfl_xor(mt, o));
            float se = 0.f;
            #pragma unroll
            for (int jt = 0; jt < 4; ++jt) se += __expf(v[jt] - mt);
            #pragma unroll
            for (int o = 1; o < 16; o <<= 1) se += __shfl_xor(se, o);
            if (lid == 0) { pm2[rlocal][wave >> 1] = mt; ps2[rlocal][wave >> 1] = se; }
        }
    }
    __syncthreads();
    if (t < 128) {
        const float m0 = pm2[t][0], m1 = pm2[t][1];
        const float mm = fmaxf(m0, m1);
        const float ss = ps2[t][0] * __expf(m0 - mm) + ps2[t][1] * __expf(m1 - mm);
        pstats[(size_t)(z * 4 + blockIdx.y) * MM + row0 + t] = make_float2(mm, ss);
    }
}

// ---------------------------------------------------------------------------
// mask_xy output: Mo[z][i][j] = mask_x[bq][i] && mask_y[s][j]. grid = (128, 64)
// ---------------------------------------------------------------------------
__global__ __launch_bounds__(256) void maskxy_kernel(
    const int* __restrict__ mask_x, const int* __restrict__ mask_y,
    float* __restrict__ Mo)
{
    const int z = blockIdx.y;
    const int n = z >> 3, s = z & 7, bq = s * 8 + n;
    const int i = blockIdx.x * 4 + (threadIdx.x >> 6);
    const int lane = threadIdx.x & 63;
    const bool mr = mask_x[bq * MM + i] != 0;
    float* row = Mo + ((size_t)z * MM + i) * MM;
    const int4* my = (const int4*)(mask_y + s * MM);
    #pragma unroll
    for (int g = 0; g < 2; ++g) {
        const int c4 = g * 64 + lane;
        int4 m4 = my[c4];
        float4 v = mr ? make_float4(m4.x ? 1.f : 0.f, m4.y ? 1.f : 0.f,
                                    m4.z ? 1.f : 0.f, m4.w ? 1.f : 0.f)
                      : make_float4(0.f, 0.f, 0.f, 0.f);
        *(float4*)(row + c4 * 4) = v;
    }
}

// ---------------------------------------------------------------------------
// Merge 4 col-block partials per row -> (max, 1/sum). All-masked rows ->
// (NEG_FILL, 1/512) = uniform softmax (jax match). grid = nrows/256.
// ---------------------------------------------------------------------------
__global__ __launch_bounds__(256) void reduce4_kernel(
    const float2* __restrict__ p, float2* __restrict__ st)
{
    const int row = blockIdx.x * 256 + threadIdx.x;
    const int z = row >> 9, rl = row & 511;
    float m = -3.4e38f, s = 0.f;
    #pragma unroll
    for (int by = 0; by < 4; ++by) {
        float2 v = p[(size_t)(z * 4 + by) * MM + rl];
        float nm = fmaxf(m, v.x);
        s = s * __expf(m - nm) + v.y * __expf(v.x - nm);
        m = nm;
    }
    st[row] = make_float2(m, 1.0f / s);
}

// ---------------------------------------------------------------------------
// Context via MFMA (plain bf16, K'=512). A = exp(S-m) manual-staged (pad 72);
// B = Vt async (unpadded 64). grid = (4, 2, nbatch)
// ---------------------------------------------------------------------------
__global__ __launch_bounds__(256) void ctx_kernel(
    const float* __restrict__ Sbase, const float2* __restrict__ stats,
    const unsigned short* __restrict__ Vt_base, float* __restrict__ Obase)
{
    const int b = blockIdx.z;
    const float*          S  = Sbase + (size_t)b * MM * MM;
    const float2*         st = stats + (size_t)b * MM;
    const unsigned short* Vt = Vt_base + (size_t)b * DD * MM;
    float*                O  = Obase + (size_t)b * MM * DD;

    const int row0 = blockIdx.x * 128;
    const int col0 = blockIdx.y * 128;

    __shared__ unsigned short Ab[128][72];
    __shared__ unsigned short Bb[128][64];

    const int t = threadIdx.x;
    const int wave = t >> 6, lane = t & 63, quad = lane >> 4, lid = lane & 15;
    const int wrow = (wave & 1) * 64, wcol = (wave >> 1) * 64;

    f32x4 acc[4][4];
    #pragma unroll
    for (int i = 0; i < 4; ++i)
        #pragma unroll
        for (int j = 0; j < 4; ++j) acc[i][j] = (f32x4){0.f, 0.f, 0.f, 0.f};

    // per-thread staging rows fixed across ck: hoist the row-max loads
    float pmv[4];
    #pragma unroll
    for (int s = 0; s < 4; ++s) pmv[s] = st[row0 + ((s * 256 + t) >> 3)].x;

    for (int ck = 0; ck < 8; ++ck) {
        #pragma unroll
        for (int s = 0; s < 4; ++s) {
            const int c   = s * 256 + wave * 64 + lane;
            const int row = c >> 3;
            const int j8  = (c & 7) * 8;
            gld16(Vt + (size_t)(col0 + row) * MM + ck * 64 + j8,
                  &Bb[0][0] + (size_t)(s * 256 + wave * 64) * 8);
        }
        #pragma unroll
        for (int s = 0; s < 4; ++s) {
            const int c   = s * 256 + t;
            const int row = c >> 3;
            const int j8  = (c & 7) * 8;
            const float* sp = S + (size_t)(row0 + row) * MM + ck * 64 + j8;
            float4 v0 = *(const float4*)sp;
            float4 v1 = *(const float4*)(sp + 4);
            const float pm = pmv[s];
            short8 pk;
            pk[0] = (short)rne_bf16(__expf(v0.x - pm));
            pk[1] = (short)rne_bf16(__expf(v0.y - pm));
            pk[2] = (short)rne_bf16(__expf(v0.z - pm));
            pk[3] = (short)rne_bf16(__expf(v0.w - pm));
            pk[4] = (short)rne_bf16(__expf(v1.x - pm));
            pk[5] = (short)rne_bf16(__expf(v1.y - pm));
            pk[6] = (short)rne_bf16(__expf(v1.z - pm));
            pk[7] = (short)rne_bf16(__expf(v1.w - pm));
            *(short8*)&Ab[row][j8] = pk;
        }
        __syncthreads();
        mfma_tiles<72,64>(Ab, Bb, 0,  wrow, wcol, lid, quad, acc);
        mfma_tiles<72,64>(Ab, Bb, 32, wrow, wcol, lid, quad, acc);
        __syncthreads();
    }

    #pragma unroll
    for (int i = 0; i < 4; ++i) {
        const int rgb = row0 + wrow + i * 16 + quad * 4;
        float inv[4];
        #pragma unroll
        for (int r = 0; r < 4; ++r) inv[r] = st[rgb + r].y;
        #pragma unroll
        for (int jt = 0; jt < 4; ++jt) {
            const int col = col0 + wcol + jt * 16 + lid;
            #pragma unroll
            for (int r = 0; r < 4; ++r)
                O[(size_t)(rgb + r) * DD + col] = acc[i][jt][r] * inv[r];
        }
    }
}

// ---------------------------------------------------------------------------
// In-place softmax transform of the scores_xy slot -> probs_xy.
// ---------------------------------------------------------------------------
__global__ __launch_bounds__(128) void softmax_apply(
    float* __restrict__ S, const float2* __restrict__ stats)
{
    const int row = blockIdx.x;
    const float2 st = stats[row];
    float4* r = (float4*)(S + (size_t)row * MM) + threadIdx.x;
    float4 v = *r;
    v.x = __expf(v.x - st.x) * st.y;
    v.y = __expf(v.y - st.x) * st.y;
    v.z = __expf(v.z - st.x) * st.y;
    v.w = __expf(v.w - st.x) * st.y;
    *r = v;
}

// ---------------------------------------------------------------------------
// y_len: one block per s, 64-lane reduce; lane n<8 writes out[n*8+s].
// ---------------------------------------------------------------------------
__global__ void ylen_kernel(const int* __restrict__ mask_y, float* __restrict__ out)
{
    const int s = blockIdx.x;
    const int lane = threadIdx.x;
    int c = 0;
    #pragma unroll
    for (int k = 0; k < 8; ++k) c += (mask_y[s * MM + k * 64 + lane] != 0);
    #pragma unroll
    for (int off = 32; off; off >>= 1) c += __shfl_xor(c, off);
    if (lane < 8) out[lane * 8 + s] = (float)c;
}

// ---------------------------------------------------------------------------
extern "C" void kernel_launch(void* const* d_in, const int* in_sizes, int n_in,
                              void* d_out, int out_size, void* d_ws, size_t ws_size,
                              hipStream_t stream)
{
    const float* x      = (const float*)d_in[0];
    const float* y      = (const float*)d_in[1];
    const int*   mask_x = (const int*)d_in[2];
    const int*   mask_y = (const int*)d_in[3];
    const float* Wq     = (const float*)d_in[4];
    const float* Wk     = (const float*)d_in[5];
    const float* Wv     = (const float*)d_in[6];
    float* out = (float*)d_out;

    // Workspace (~136 MB): Xh|Xl|Wh|Wl|Qh|Ql|Kh|Kl|Vt | stats | pstats
    unsigned short* Xh = (unsigned short*)d_ws;        // 36864*256 = 9437184
    unsigned short* Xl = Xh + 9437184;
    unsigned short* Wh = Xl + 9437184;                 // 3*65536   = 196608
    unsigned short* Wl = Wh + 196608;
    unsigned short* Qh = Wl + 196608;
    unsigned short* Ql = Qh + 9437184;
    unsigned short* Kh = Ql + 9437184;
    unsigned short* Kl = Kh + 9437184;
    unsigned short* Vt = Kl + 9437184;                 // 72*256*512 = 9437184
    float2* stats_x  = (float2*)(Vt + 9437184);
    float2* stats_y  = stats_x + ROWS_X;
    float2* stats_xy = stats_y + ROWS_Y;
    float2* ps_x  = stats_xy + ROWS_X;                 // 64*4*512
    float2* ps_y  = ps_x + 64 * 4 * 512;               // 8*4*512
    float2* ps_xy = ps_y + 8 * 4 * 512;                // 64*4*512

    // Output slots (floats, concatenated in reference return order)
    float* out_ctx_x = out;                 // 64*512*256   = 8388608
    float* out_ctx_y = out + 8388608;       // 8*512*256    = 1048576
    float* out_sx    = out + 9437184;       // 64*512*512   = 16777216
    float* out_sy    = out + 26214400;      // 8*512*512    = 2097152
    float* out_pxy   = out + 28311552;      // 8*8*512*512  = 16777216
    float* out_mxy   = out + 45088768;      // 8*8*512*512  = 16777216
    float* out_ylen  = out + 61865984;      // 8*8          = 64

    // 1. fp32 -> (h,l) bf16 planes
    conv_kernel<<<4704, 256, 0, stream>>>(x, y, Wq, Wk, Wv, Xh, Xl, Wh, Wl);

    // 2. Projections (pure-async MFMA), coalesced transposed epilogues
    proj_kernel<<<dim3(288, 2, 3), 256, 0, stream>>>(Xh, Xl, Wh, Wl,
                                                     Qh, Ql, Kh, Kl, Vt);

    const unsigned short* Qh_y = Qh + (size_t)ROWS_X * 256;
    const unsigned short* Ql_y = Ql + (size_t)ROWS_X * 256;
    const unsigned short* Kh_y = Kh + (size_t)ROWS_X * 256;
    const unsigned short* Kl_y = Kl + (size_t)ROWS_X * 256;

    // 3. Masked scores + fused softmax partials
    scores_kernel<<<dim3(4, 4, 64), 256, 0, stream>>>(Qh,   Ql,   Kh,   Kl,
        mask_x, mask_x, out_sx, ps_x, 0);
    scores_kernel<<<dim3(4, 4, 8),  256, 0, stream>>>(Qh_y, Ql_y, Kh_y, Kl_y,
        mask_y, mask_y, out_sy, ps_y, 1);
    scores_kernel<<<dim3(4, 4, 64), 256, 0, stream>>>(Qh,   Ql,   Kh_y, Kl_y,
        mask_x, mask_y, out_pxy, ps_xy, 2);

    // 3b. mask_xy (pure outer-product, coalesced)
    maskxy_kernel<<<dim3(128, 64), 256, 0, stream>>>(mask_x, mask_y, out_mxy);

    // 4. Merge partials -> (max, 1/sum)
    reduce4_kernel<<<ROWS_X / 256, 256, 0, stream>>>(ps_x,  stats_x);
    reduce4_kernel<<<ROWS_Y / 256, 256, 0, stream>>>(ps_y,  stats_y);
    reduce4_kernel<<<ROWS_X / 256, 256, 0, stream>>>(ps_xy, stats_xy);

    // 5. Context GEMMs (MFMA, exp fused on A-stage)
    ctx_kernel<<<dim3(4, 2, 64), 256, 0, stream>>>(out_sx, stats_x, Vt, out_ctx_x);
    ctx_kernel<<<dim3(4, 2, 8),  256, 0, stream>>>(out_sy, stats_y,
                                                   Vt + (size_t)64 * DD * MM, out_ctx_y);

    // 6. scores_xy -> probs_xy in place
    softmax_apply<<<ROWS_X, 128, 0, stream>>>(out_pxy, stats_xy);

    // 7. y_len
    ylen_kernel<<<8, 64, 0, stream>>>(mask_y, out_ylen);
}